// Round 2
// baseline (428.454 us; speedup 1.0000x reference)
//
#include <hip/hip_runtime.h>
#include <stdint.h>

// out[b,s,d] = sum_t w[b,s,t] * x[b,t,d]
//   w = softmax(uniform(key=42, (4,4096,4096), -0.1, 0.1), -1) / denom,
//   denom[s] = sum_{b,t} softmax = 4 exactly.
// JAX >= 0.4.36 default: threefry_partitionable=True. Stream per element with
// flat index f (row-major over (4,4096,4096), f < 2^26):
//   (x0,x1) = (0,f) + key(0,42) -> 20-round threefry2x32 -> bits = x0 ^ x1
//   u = max(-0.1, ((bits>>9)|0x3F800000 as float - 1) * 0.2 - 0.1)
// softmax max-subtraction cancels algebraically: out = sum exp(u) x / (4 sum exp(u)).

#define S_ 4096
#define D_ 64
#define TK 64
#define TS 32
#define WS 34   // W LDS stride (64 rows of kl, 32+2 pad sl entries)

__device__ __forceinline__ uint32_t rotl32(uint32_t x, unsigned r) {
    return (x << r) | (x >> (32u - r));
}

// Partitionable-threefry 32-bit draw for counter (0, f), key (0, 42).
__device__ __forceinline__ uint32_t threefry_bits(uint32_t f) {
    const uint32_t k0 = 0u, k1 = 42u;
    const uint32_t k2 = 0x1BD11BDAu ^ k0 ^ k1;
    uint32_t x0 = k0;          // 0 + ks[0]
    uint32_t x1 = f + k1;      // f + ks[1]
#define TFR(r) { x0 += x1; x1 = rotl32(x1, (r)); x1 ^= x0; }
    TFR(13) TFR(15) TFR(26) TFR(6)
    x0 += k1; x1 += k2 + 1u;
    TFR(17) TFR(29) TFR(16) TFR(24)
    x0 += k2; x1 += k0 + 2u;
    TFR(13) TFR(15) TFR(26) TFR(6)
    x0 += k0; x1 += k1 + 3u;
    TFR(17) TFR(29) TFR(16) TFR(24)
    x0 += k1; x1 += k2 + 4u;
    TFR(13) TFR(15) TFR(26) TFR(6)
    x0 += k2; x1 += k0 + 5u;
#undef TFR
    return x0 ^ x1;            // <=32-bit branch: xor of the two output words
}

__device__ __forceinline__ float uniform_exp(uint32_t bits) {
    uint32_t fb = (bits >> 9) | 0x3F800000u;
    float f = __uint_as_float(fb) - 1.0f;
    float u = fmaxf(-0.1f, fmaf(f, 0.2f, -0.1f));
    return __expf(u);
}

__global__ __launch_bounds__(256, 2) void fused_rand_attn(
    const float* __restrict__ x, float* __restrict__ out)
{
    const int tid = threadIdx.x;
    const int bid = blockIdx.x;
    const int b  = bid & 3;             // one batch per block now (no word sharing)
    const int s0 = (bid >> 2) * TS;     // row-tile start

    __shared__ float Xl[TK][D_];        // 16 KiB
    __shared__ float Wl[TK][WS];        // 8.5 KiB, Wl[kl][sl]
    __shared__ float Zl[TS][8];
    __shared__ float Zf[TS];

    const int dc4 = (tid & 15) << 2;    // d offset (float4)
    const int sr  = tid >> 4;           // row-pair 0..15 -> rows 2sr, 2sr+1
    const int zs  = tid & 31;           // z-phase row
    const int ze  = tid >> 5;           // z-phase k-eighth 0..7

    float acc[2][4] = {{0.f,0.f,0.f,0.f},{0.f,0.f,0.f,0.f}};
    float zpart = 0.0f;

    const float* __restrict__ xb = x + (size_t)b * (S_ * D_);
    const uint32_t fbase = ((uint32_t)b << 24) + (uint32_t)(s0 * S_);

    for (int kt = 0; kt < S_ / TK; ++kt) {
        const int k0 = kt * TK;

        // Stage X tile to regs first; latency hides under PRNG compute.
        float4 xr[4];
#pragma unroll
        for (int it = 0; it < 4; ++it) {
            const int idx = it * 256 + tid;      // 0..1023 -> (k, d4)
            const int kk  = idx >> 4;
            const int dd  = (idx & 15) << 2;
            xr[it] = *(const float4*)&xb[(k0 + kk) * D_ + dd];
        }

        __syncthreads();   // previous tile fully consumed

        // Generate W tile: 32 rows x 64 cols, 8 threefry calls/thread.
        // sl = c&31, kl = c>>5: lanes write distinct banks (2-way across halves).
#pragma unroll 4
        for (int p = 0; p < 8; ++p) {
            const int c  = p * 256 + tid;
            const int sl = c & 31;
            const int kl = c >> 5;
            const uint32_t f = fbase + (uint32_t)(sl * S_ + k0 + kl);
            Wl[kl][sl] = uniform_exp(threefry_bits(f));
        }

        // Commit staged X to LDS.
#pragma unroll
        for (int it = 0; it < 4; ++it) {
            const int idx = it * 256 + tid;
            const int kk  = idx >> 4;
            const int dd  = (idx & 15) << 2;
            *(float4*)&Xl[kk][dd] = xr[it];
        }

        __syncthreads();

        // Row-sum partials (accumulate across all k-tiles in registers).
#pragma unroll
        for (int kk = 0; kk < 8; ++kk)
            zpart += Wl[ze * 8 + kk][zs];

        // Register-tiled FMA: 2 rows x 4 d-cols per thread per k.
#pragma unroll 8
        for (int k = 0; k < TK; ++k) {
            const float4 xa = *(const float4*)&Xl[k][dc4];
            const float2 w2 = *(const float2*)&Wl[k][2 * sr];
            acc[0][0] += w2.x * xa.x; acc[0][1] += w2.x * xa.y;
            acc[0][2] += w2.x * xa.z; acc[0][3] += w2.x * xa.w;
            acc[1][0] += w2.y * xa.x; acc[1][1] += w2.y * xa.y;
            acc[1][2] += w2.y * xa.z; acc[1][3] += w2.y * xa.w;
        }
    }

    // Final Z reduction across the 8 k-eighths.
    Zl[zs][ze] = zpart;
    __syncthreads();
    if (tid < TS) {
        float z = 0.f;
#pragma unroll
        for (int e = 0; e < 8; ++e) z += Zl[tid][e];
        Zf[tid] = z;
    }
    __syncthreads();

    // Epilogue: scale by 1/(4*Z) (softmax denom * exact column-renorm denom 4).
#pragma unroll
    for (int r = 0; r < 2; ++r) {
        const int row = 2 * sr + r;
        const float scale = 1.0f / (4.0f * Zf[row]);
        float4 v;
        v.x = acc[r][0] * scale;
        v.y = acc[r][1] * scale;
        v.z = acc[r][2] * scale;
        v.w = acc[r][3] * scale;
        *(float4*)&out[((size_t)b * S_ + (s0 + row)) * D_ + dc4] = v;
    }
}

extern "C" void kernel_launch(void* const* d_in, const int* in_sizes, int n_in,
                              void* d_out, int out_size, void* d_ws, size_t ws_size,
                              hipStream_t stream) {
    const float* x = (const float*)d_in[0];   // [4,4096,64] fp32
    // d_in[1] (attn_mask) is dead in the reference; unused.
    float* out = (float*)d_out;               // [4,4096,64] fp32
    (void)d_ws; (void)ws_size; (void)in_sizes; (void)n_in; (void)out_size;
    // grid: 4 batches x 128 row-tiles of 32 rows = 512 blocks (2 per CU)
    hipLaunchKernelGGL(fused_rand_attn, dim3(512), dim3(256), 0, stream, x, out);
}

// Round 3
// 182.671 us; speedup vs baseline: 2.3455x; 2.3455x over previous
//
#include <hip/hip_runtime.h>
#include <hip/hip_bf16.h>
#include <stdint.h>

// out[b,s,d] = sum_t w[b,s,t] * x[b,t,d]
//   w = softmax(uniform(key=42, (4,4096,4096), -0.1, 0.1), -1) / denom,
//   denom[s] = sum_{b,t} softmax = 4 exactly (softmax rows sum to 1).
// PRNG: JAX partitionable threefry (verified round 2): counter (0, flat_idx),
// key (0,42), draw = x0 ^ x1; bits -> [1,2) -> [0,1) -> [-0.1, 0.1).
// GEMM on MFMA bf16 16x16x32. W and X^T both stored [row][k] in LDS and loaded
// with the SAME k-contiguous lane mapping, so any HW k-permutation cancels.

#define S_ 4096
#define D_ 64
#define TK 64
#define TS 16
#define LDK 72   // LDS k-stride (bf16 elems): 144B rows -> 2-way banks, 16B aligned

typedef __attribute__((ext_vector_type(8))) short short8v;   // 8 bf16 = 4 VGPR
typedef __attribute__((ext_vector_type(4))) short short4v;   // 8B
typedef __attribute__((ext_vector_type(4))) float floatx4;

__device__ __forceinline__ uint32_t rotl32(uint32_t x, unsigned r) {
    return (x << r) | (x >> (32u - r));
}

// Partitionable-threefry 32-bit draw for counter (0, f), key (0, 42). (verified)
__device__ __forceinline__ uint32_t threefry_bits(uint32_t f) {
    const uint32_t k0 = 0u, k1 = 42u;
    const uint32_t k2 = 0x1BD11BDAu ^ k0 ^ k1;
    uint32_t x0 = k0;
    uint32_t x1 = f + k1;
#define TFR(r) { x0 += x1; x1 = rotl32(x1, (r)); x1 ^= x0; }
    TFR(13) TFR(15) TFR(26) TFR(6)
    x0 += k1; x1 += k2 + 1u;
    TFR(17) TFR(29) TFR(16) TFR(24)
    x0 += k2; x1 += k0 + 2u;
    TFR(13) TFR(15) TFR(26) TFR(6)
    x0 += k0; x1 += k1 + 3u;
    TFR(17) TFR(29) TFR(16) TFR(24)
    x0 += k1; x1 += k2 + 4u;
    TFR(13) TFR(15) TFR(26) TFR(6)
    x0 += k2; x1 += k0 + 5u;
#undef TFR
    return x0 ^ x1;
}

__device__ __forceinline__ float uniform_exp(uint32_t bits) {
    uint32_t fb = (bits >> 9) | 0x3F800000u;
    float f = __uint_as_float(fb) - 1.0f;
    float u = fmaxf(-0.1f, fmaf(f, 0.2f, -0.1f));
    return __expf(u);
}

__device__ __forceinline__ short f2bf(float v) {
    __hip_bfloat16 h = __float2bfloat16(v);   // RNE hw convert
    return __builtin_bit_cast(short, h);
}

__global__ __launch_bounds__(256, 4) void fused_rand_attn_mfma(
    const float* __restrict__ x, float* __restrict__ out)
{
    const int tid = threadIdx.x;
    // XCD-aware swizzle: 1024 blocks, 8 XCDs -> each XCD owns a contiguous
    // 128-tile chunk (single batch half) => per-XCD X working set 1MB, L2-fits.
    const int bid = (blockIdx.x & 7) * 128 + (blockIdx.x >> 3);
    const int b   = bid >> 8;            // batch 0..3
    const int s0  = (bid & 255) * TS;    // row-tile start

    __shared__ short Wl[2][TS][LDK];     // A tiles (bf16), double-buffered
    __shared__ short XTl[2][D_][LDK];    // B tiles = X^T (bf16), double-buffered
    __shared__ float Zl[TS][17];
    __shared__ float Zf[TS];

    const int lane = tid & 63;
    const int w    = tid >> 6;           // wave id 0..3 -> owns d-cols 16w..16w+15
    const int sl   = tid & 15;           // PRNG row (fixed per thread)
    const int kg   = tid >> 4;           // PRNG k-subindex 0..15
    const int kk   = (tid & 15) * 4;     // X staging: k-base (4 rows)
    const int dd   = (tid >> 4) * 4;     // X staging: d-base (4 cols)
    const int lt   = lane & 15;
    const int lh   = lane >> 4;

    floatx4 acc = {0.f, 0.f, 0.f, 0.f};
    float zpart = 0.0f;

    const float* __restrict__ xb = x + (size_t)b * (S_ * D_);
    const uint32_t fbase = ((uint32_t)b << 24) + ((uint32_t)(s0 + sl) << 12);

    for (int kt = 0; kt < S_ / TK; ++kt) {
        const int k0  = kt << 6;
        const int buf = kt & 1;

        // ---- issue X staging loads early (latency hides under PRNG) ----
        union { floatx4 v; float f[4]; } xr[4];
#pragma unroll
        for (int i = 0; i < 4; ++i)
            xr[i].v = *(const floatx4*)&xb[(size_t)(k0 + kk + i) * D_ + dd];

        // ---- W generation: 4 draws, row sl, cols kl = p*16+kg ----
        float ev[4];
#pragma unroll
        for (int p = 0; p < 4; ++p) {
            const uint32_t f = fbase + (uint32_t)(k0 + p * 16 + kg);
            ev[p] = uniform_exp(threefry_bits(f));
            zpart += ev[p];               // fp32 row-sum (exact softmax denom)
        }
#pragma unroll
        for (int p = 0; p < 4; ++p)
            Wl[buf][sl][p * 16 + kg] = f2bf(ev[p]);

        // ---- transpose-stage X tile to bf16 LDS: XTl[d][k] ----
#pragma unroll
        for (int j = 0; j < 4; ++j) {
            short4v v4 = { f2bf(xr[0].f[j]), f2bf(xr[1].f[j]),
                           f2bf(xr[2].f[j]), f2bf(xr[3].f[j]) };
            *(short4v*)&XTl[buf][dd + j][kk] = v4;
        }

        __syncthreads();   // gen(buf) complete; reads(buf) below; next iter
                           // writes buf^1, so one barrier per kt suffices.

        // ---- MFMA: A = W[16s x 64k], B = X^T[16d x 64k], 2 k-chunks ----
#pragma unroll
        for (int kc = 0; kc < 2; ++kc) {
            const int ko = kc * 32 + 8 * lh;   // same k mapping for A and B
            short8v a  = *(const short8v*)&Wl[buf][lt][ko];
            short8v bv = *(const short8v*)&XTl[buf][w * 16 + lt][ko];
            acc = __builtin_amdgcn_mfma_f32_16x16x32_bf16(a, bv, acc, 0, 0, 0);
        }
    }

    // ---- Z reduction ----
    Zl[sl][kg] = zpart;
    __syncthreads();
    if (tid < TS) {
        float z = 0.f;
#pragma unroll
        for (int c = 0; c < 16; ++c) z += Zl[tid][c];
        Zf[tid] = z;
    }
    __syncthreads();

    // ---- epilogue: C layout col=lane&15 (d), row=(lane>>4)*4+reg (s) ----
    const int n = w * 16 + lt;
#pragma unroll
    for (int r = 0; r < 4; ++r) {
        const int row = lh * 4 + r;
        const float scale = 1.0f / (4.0f * Zf[row]);
        out[((size_t)b * S_ + (s0 + row)) * D_ + n] = acc[r] * scale;
    }
}

extern "C" void kernel_launch(void* const* d_in, const int* in_sizes, int n_in,
                              void* d_out, int out_size, void* d_ws, size_t ws_size,
                              hipStream_t stream) {
    const float* x = (const float*)d_in[0];   // [4,4096,64] fp32
    // d_in[1] (attn_mask) is dead in the reference; unused.
    float* out = (float*)d_out;               // [4,4096,64] fp32
    (void)d_ws; (void)ws_size; (void)in_sizes; (void)n_in; (void)out_size;
    // 4 batches x 256 row-tiles of 16 = 1024 blocks, 256 threads (4 waves)
    hipLaunchKernelGGL(fused_rand_attn_mfma, dim3(1024), dim3(256), 0, stream,
                       x, out);
}